// Round 7
// baseline (280.616 us; speedup 1.0000x reference)
//
#include <hip/hip_runtime.h>

#define NPTS 100000
#define P 64
#define C 128
#define CHUNKS 16
#define CHUNK_PTS 6250      // 16 * 6250 = 100000
#define CHUNK_PAD 6400      // padded to multiple of 256
#define NWAVES 6250         // 100000 / 16 points per wave

typedef __bf16 bf16_t;
typedef __bf16 bf16x8 __attribute__((ext_vector_type(8)));
typedef float floatx4 __attribute__((ext_vector_type(4)));

// Workspace layout (bytes):
//   [0,      65536)    W1t bf16 [256][128]   (s1 folded, transposed: [n][k])
//   [65536, 131072)    W2t bf16 [128][256]   (s2 folded, transposed)
//   [131072,163840)    Wat bf16 [128][128]   (transposed)
//   [163840, +51.2MB)  rec bf16 [NPTS][256]  (a[128] | h2[128] per point)
//   then               partial f32 [64][16][4][128]  (2 MB)

__global__ __launch_bounds__(256) void prep_kernel(
    const float* __restrict__ W1, const float* __restrict__ s1,
    const float* __restrict__ W2, const float* __restrict__ s2,
    const float* __restrict__ Wa,
    bf16_t* __restrict__ W1t, bf16_t* __restrict__ W2t, bf16_t* __restrict__ Wat)
{
  int i0 = blockIdx.x * blockDim.x + threadIdx.x;
  int stride = gridDim.x * blockDim.x;
  for (int i = i0; i < 256 * 128; i += stride) {          // W1t[n][k] = W1[k][n]*s1[n]
    int n = i >> 7, k = i & 127;
    W1t[i] = (bf16_t)(W1[k * 256 + n] * s1[n]);
  }
  for (int i = i0; i < 128 * 256; i += stride) {          // W2t[n][k] = W2[k][n]*s2[n]
    int n = i >> 8, k = i & 255;
    W2t[i] = (bf16_t)(W2[k * 128 + n] * s2[n]);
  }
  for (int i = i0; i < 128 * 128; i += stride) {          // Wat[n][k] = Wa[k][n]
    int n = i >> 7, k = i & 127;
    Wat[i] = (bf16_t)(Wa[k * 128 + n]);
  }
}

// Phase A, BARRIER-FREE: one wave owns 16 points end-to-end (m-split).
// feature(regs) -> G1 -> wave-private LDS transpose -> G2 -> transpose ->
// Ga -> transpose -> rec + logit. Zero __syncthreads; waves independent.
#define HSTRIDE 264   // bf16 row stride: 528B, 16B-aligned, 132dw = +4 banks/row

__global__ __launch_bounds__(256) void main_kernel(
    const float* __restrict__ feature,
    const float* __restrict__ b1, const float* __restrict__ b2,
    const float* __restrict__ W3, const float* __restrict__ b3,
    const bf16_t* __restrict__ W1t, const bf16_t* __restrict__ W2t,
    const bf16_t* __restrict__ Wat,
    bf16_t* __restrict__ rec, float* __restrict__ out_logit)
{
  __shared__ __align__(16) bf16_t hS[4][16 * HSTRIDE];   // per-wave scratch, 33792 B

  const int tid  = threadIdx.x;
  const int wave = tid >> 6, lane = tid & 63;
  const int q = lane >> 4, l = lane & 15;
  const int wid = blockIdx.x * 4 + wave;
  if (wid >= NWAVES) return;
  const int m0 = wid * 16;             // this wave's 16 points
  bf16_t* hw = &hS[wave][0];

  // ---- feature A-frags: lane(q,l) holds pt m0+l, chs kt*32+q*8..+8 ----
  bf16x8 afeat[4];
#pragma unroll
  for (int kt = 0; kt < 4; ++kt) {
    const float* src = feature + (size_t)(m0 + l) * C + kt * 32 + q * 8;
    float4 v0 = *(const float4*)(src);
    float4 v1 = *(const float4*)(src + 4);
    bf16x8 o = {(bf16_t)v0.x, (bf16_t)v0.y, (bf16_t)v0.z, (bf16_t)v0.w,
                (bf16_t)v1.x, (bf16_t)v1.y, (bf16_t)v1.z, (bf16_t)v1.w};
    afeat[kt] = o;
  }

  // ---- bias prefetch (independent loads, hoistable) ----
  float b1r[16], b2r[8];
#pragma unroll
  for (int nt = 0; nt < 16; ++nt) b1r[nt] = b1[nt * 16 + l];
#pragma unroll
  for (int nt = 0; nt < 8; ++nt)  b2r[nt] = b2[nt * 16 + l];

  const floatx4 zero4 = {0.f, 0.f, 0.f, 0.f};

  // ---- GEMM1: h[16][256] = relu(feat @ W1' + b1), full n-range this wave ----
  {
    floatx4 acc[16];
#pragma unroll
    for (int nt = 0; nt < 16; ++nt) acc[nt] = zero4;
#pragma unroll
    for (int nt = 0; nt < 16; ++nt)
#pragma unroll
      for (int kt = 0; kt < 4; ++kt) {
        bf16x8 bfr = *(const bf16x8*)(W1t + (nt * 16 + l) * 128 + kt * 32 + q * 8);
        acc[nt] = __builtin_amdgcn_mfma_f32_16x16x32_bf16(afeat[kt], bfr, acc[nt], 0, 0, 0);
      }
    // C-layout: lane(q,l) holds h[pt=q*4+r][ch=nt*16+l] -> wave-private LDS
#pragma unroll
    for (int nt = 0; nt < 16; ++nt)
#pragma unroll
      for (int r = 0; r < 4; ++r)
        hw[(q * 4 + r) * HSTRIDE + nt * 16 + l] = (bf16_t)fmaxf(acc[nt][r] + b1r[nt], 0.f);
  }

  // ---- read h back in A-layout (same wave; lgkmcnt ordering only) ----
  bf16x8 ah[8];
#pragma unroll
  for (int kt = 0; kt < 8; ++kt)
    ah[kt] = *(const bf16x8*)(hw + l * HSTRIDE + kt * 32 + q * 8);

  // ---- GEMM2: h2[16][128] = relu(h @ W2' + b2) ----
  {
    floatx4 acc[8];
#pragma unroll
    for (int nt = 0; nt < 8; ++nt) acc[nt] = zero4;
#pragma unroll
    for (int nt = 0; nt < 8; ++nt)
#pragma unroll
      for (int kt = 0; kt < 8; ++kt) {
        bf16x8 bfr = *(const bf16x8*)(W2t + (nt * 16 + l) * 256 + kt * 32 + q * 8);
        acc[nt] = __builtin_amdgcn_mfma_f32_16x16x32_bf16(ah[kt], bfr, acc[nt], 0, 0, 0);
      }
#pragma unroll
    for (int nt = 0; nt < 8; ++nt)
#pragma unroll
      for (int r = 0; r < 4; ++r)
        hw[(q * 4 + r) * HSTRIDE + nt * 16 + l] = (bf16_t)fmaxf(acc[nt][r] + b2r[nt], 0.f);
  }

  // ---- h2 in A-layout (used by Ga, rec, logit) ----
  bf16x8 ah2[4];
#pragma unroll
  for (int kt = 0; kt < 4; ++kt)
    ah2[kt] = *(const bf16x8*)(hw + l * HSTRIDE + kt * 32 + q * 8);

  // ---- GEMMa: a[16][128] = h2 @ Wa ----
  {
    floatx4 acc[8];
#pragma unroll
    for (int nt = 0; nt < 8; ++nt) acc[nt] = zero4;
#pragma unroll
    for (int nt = 0; nt < 8; ++nt)
#pragma unroll
      for (int kt = 0; kt < 4; ++kt) {
        bf16x8 bfr = *(const bf16x8*)(Wat + (nt * 16 + l) * 128 + kt * 32 + q * 8);
        acc[nt] = __builtin_amdgcn_mfma_f32_16x16x32_bf16(ah2[kt], bfr, acc[nt], 0, 0, 0);
      }
#pragma unroll
    for (int nt = 0; nt < 8; ++nt)
#pragma unroll
      for (int r = 0; r < 4; ++r)
        hw[(q * 4 + r) * HSTRIDE + nt * 16 + l] = (bf16_t)acc[nt][r];
  }

  // ---- a in A-layout; write rec = {a[128] | h2[128]} coalesced 16B stores ----
#pragma unroll
  for (int kt = 0; kt < 4; ++kt) {
    bf16x8 aA = *(const bf16x8*)(hw + l * HSTRIDE + kt * 32 + q * 8);
    *(bf16x8*)(rec + (size_t)(m0 + l) * 256 + kt * 32 + q * 8) = aA;
  }
#pragma unroll
  for (int kt = 0; kt < 4; ++kt)
    *(bf16x8*)(rec + (size_t)(m0 + l) * 256 + 128 + kt * 32 + q * 8) = ah2[kt];

  // ---- logit from h2 A-frags: lane sums its 32 chs, reduce across quads ----
  {
    float lsum = 0.f;
#pragma unroll
    for (int kt = 0; kt < 4; ++kt) {
      const float* w3p = W3 + kt * 32 + q * 8;
      float4 w0 = *(const float4*)(w3p);
      float4 w1 = *(const float4*)(w3p + 4);
      lsum += (float)ah2[kt][0] * w0.x + (float)ah2[kt][1] * w0.y +
              (float)ah2[kt][2] * w0.z + (float)ah2[kt][3] * w0.w +
              (float)ah2[kt][4] * w1.x + (float)ah2[kt][5] * w1.y +
              (float)ah2[kt][6] * w1.z + (float)ah2[kt][7] * w1.w;
    }
    lsum += __shfl_xor(lsum, 16);
    lsum += __shfl_xor(lsum, 32);
    if (lane < 16) out_logit[m0 + lane] = lsum + b3[0];
  }
}

// Phase B: 64 planes x 16 chunks. Scan xyz, ballot hits, wave-cooperative
// record load + register accumulation (lane owns channels 2l, 2l+1).
__global__ __launch_bounds__(256) void pool_kernel(
    const float* __restrict__ xyz, const float* __restrict__ out_logit,
    const bf16_t* __restrict__ rec,
    const float* __restrict__ ctr, const float* __restrict__ nrm,
    const float* __restrict__ pmn, const float* __restrict__ pmx,
    float* __restrict__ partial)
{
  const int plane = blockIdx.x >> 4;
  const int chunk = blockIdx.x & 15;
  const int tid = threadIdx.x, lane = tid & 63;

  __shared__ float accS[4][128];   // num_on, den_on, num_off, den_off
  for (int i = tid; i < 512; i += 256) ((float*)accS)[i] = 0.f;

  const float nx = nrm[plane * 3], ny = nrm[plane * 3 + 1], nz = nrm[plane * 3 + 2];
  const float offs = ctr[plane * 3] * nx + ctr[plane * 3 + 1] * ny + ctr[plane * 3 + 2] * nz;
  const float mnx = pmn[plane * 3], mny = pmn[plane * 3 + 1];
  const float mxx = pmx[plane * 3], mxy = pmx[plane * 3 + 1];
  __syncthreads();

  const int base = chunk * CHUNK_PTS;
  float nOn0 = 0, nOn1 = 0, dOn0 = 0, dOn1 = 0;
  float nOf0 = 0, nOf1 = 0, dOf0 = 0, dOf1 = 0;

  for (int i = tid; i < CHUNK_PAD; i += 256) {
    int pt = base + i;
    bool hit = false;
    if (i < CHUNK_PTS) {
      float x = xyz[pt * 3], y = xyz[pt * 3 + 1], z = xyz[pt * 3 + 2];
      float proj = x * nx + y * ny + z * nz;
      hit = (fabsf(proj - offs) < 0.1f) &&
            (x >= mnx) && (x < mxx) && (y >= mny) && (y < mxy);
    }
    unsigned long long m = __ballot(hit);
    while (m) {
      int lbit = __builtin_ctzll(m);
      m &= m - 1;
      int hpt = __shfl(pt, lbit);
      float lg = out_logit[hpt];                       // broadcast load
      const unsigned* r32 = (const unsigned*)(rec + (size_t)hpt * 256);
      unsigned ap = r32[lane];
      unsigned hp = r32[64 + lane];
      float a0 = __uint_as_float(ap << 16);
      float a1 = __uint_as_float(ap & 0xffff0000u);
      float h0 = __uint_as_float(hp << 16);
      float h1 = __uint_as_float(hp & 0xffff0000u);
      float e0 = __expf(a0), e1 = __expf(a1);
      if (lg > 0.f) { nOn0 += e0 * h0; nOn1 += e1 * h1; dOn0 += e0; dOn1 += e1; }
      else          { nOf0 += e0 * h0; nOf1 += e1 * h1; dOf0 += e0; dOf1 += e1; }
    }
  }

  atomicAdd(&accS[0][lane * 2],     nOn0);
  atomicAdd(&accS[0][lane * 2 + 1], nOn1);
  atomicAdd(&accS[1][lane * 2],     dOn0);
  atomicAdd(&accS[1][lane * 2 + 1], dOn1);
  atomicAdd(&accS[2][lane * 2],     nOf0);
  atomicAdd(&accS[2][lane * 2 + 1], nOf1);
  atomicAdd(&accS[3][lane * 2],     dOf0);
  atomicAdd(&accS[3][lane * 2 + 1], dOf1);
  __syncthreads();

  float* dst = partial + (size_t)blockIdx.x * 512;
  for (int i = tid; i < 512; i += 256) dst[i] = ((float*)accS)[i];
}

// Finalize: 256 threads per (sel,plane): chunk-sum split 2 ways, matvec
// reduction split 2 ways, LDS combine.
__global__ __launch_bounds__(256) void finalize_kernel(
    const float* __restrict__ partial,
    const float* __restrict__ Wm, const float* __restrict__ bm,
    const float* __restrict__ ctr, const float* __restrict__ nrm,
    const float* __restrict__ pmn, const float* __restrict__ pmx,
    float* __restrict__ out)
{
  int sel = blockIdx.x >> 6, p = blockIdx.x & 63;
  int tid = threadIdx.x, j = tid & 127, half = tid >> 7;
  __shared__ float numS[2][128], denS[2][128], aggS[128], sumS[2][128];

  const float* bp = partial + ((size_t)p * 16 + half * 8) * 512 + sel * 256;
  float num = 0.f, den = 0.f;
#pragma unroll
  for (int k = 0; k < 8; ++k) {
    num += bp[k * 512 + j];
    den += bp[k * 512 + 128 + j];
  }
  numS[half][j] = num;
  denS[half][j] = den;
  __syncthreads();
  if (tid < 128)
    aggS[tid] = (numS[0][tid] + numS[1][tid]) / (denS[0][tid] + denS[1][tid] + 1e-9f);
  __syncthreads();

  float s = 0.f;
  const int cbase = half * 64;
#pragma unroll 8
  for (int c = 0; c < 64; ++c)
    s += aggS[cbase + c] * Wm[(cbase + c) * C + j];
  sumS[half][j] = s;
  __syncthreads();

  float* dst = out + NPTS + sel * (P * 140) + p * 140;
  if (tid < 128)
    dst[tid] = fmaxf(sumS[0][tid] + sumS[1][tid] + bm[tid], 0.f);
  if (tid < 12) {
    float v;
    if (tid < 3)      v = ctr[p * 3 + tid];
    else if (tid < 6) v = nrm[p * 3 + tid - 3];
    else if (tid < 9) v = pmn[p * 3 + tid - 6];
    else              v = pmx[p * 3 + tid - 9];
    dst[C + tid] = v;
  }
}

extern "C" void kernel_launch(void* const* d_in, const int* in_sizes, int n_in,
                              void* d_out, int out_size, void* d_ws, size_t ws_size,
                              hipStream_t stream)
{
  const float* feature = (const float*)d_in[0];
  const float* xyz     = (const float*)d_in[1];
  const float* ctr     = (const float*)d_in[2];
  const float* nrm     = (const float*)d_in[3];
  const float* pmn     = (const float*)d_in[4];
  const float* pmx     = (const float*)d_in[5];
  const float* W1      = (const float*)d_in[6];
  const float* s1      = (const float*)d_in[7];
  const float* b1      = (const float*)d_in[8];
  const float* W2      = (const float*)d_in[9];
  const float* s2      = (const float*)d_in[10];
  const float* b2      = (const float*)d_in[11];
  const float* W3      = (const float*)d_in[12];
  const float* b3      = (const float*)d_in[13];
  const float* Wa      = (const float*)d_in[14];
  const float* Wm      = (const float*)d_in[15];
  const float* bm      = (const float*)d_in[16];
  float* out = (float*)d_out;

  char* ws = (char*)d_ws;
  bf16_t* W1t = (bf16_t*)(ws);
  bf16_t* W2t = (bf16_t*)(ws + 65536);
  bf16_t* Wat = (bf16_t*)(ws + 131072);
  bf16_t* rec = (bf16_t*)(ws + 163840);                       // NPTS*512 B
  float* partial = (float*)(ws + 163840 + (size_t)NPTS * 512); // 1024*512 f32

  prep_kernel<<<64, 256, 0, stream>>>(W1, s1, W2, s2, Wa, W1t, W2t, Wat);
  main_kernel<<<(NWAVES + 3) / 4, 256, 0, stream>>>(
      feature, b1, b2, W3, b3, W1t, W2t, Wat, rec, out);
  pool_kernel<<<64 * CHUNKS, 256, 0, stream>>>(
      xyz, out, rec, ctr, nrm, pmn, pmx, partial);
  finalize_kernel<<<128, 256, 0, stream>>>(partial, Wm, bm, ctr, nrm, pmn, pmx, out);
}